// Round 8
// baseline (55.173 us; speedup 1.0000x reference)
//
#include <hip/hip_runtime.h>
#include <hip/hip_bf16.h>

#define B_DIM 128
#define C_DIM 128
#define T_DIM 777
#define T_PAD 832   // 52 * 16
#define NS    52    // 16-t steps per b
#define SH    26    // steps per th half
#define P_DIM 500
#define P_PAD 512
#define NCLS  5
#define EPSV  1e-4f

typedef unsigned short u16;
typedef unsigned int   u32;
typedef __attribute__((ext_vector_type(8))) short short8;   // 8 bf16 = 4 VGPR
typedef __attribute__((ext_vector_type(4))) float f32x4;
typedef float float4u __attribute__((ext_vector_type(4), aligned(4)));  // stride 777 odd -> 4B align

__device__ __forceinline__ u32 cvt_pk_bf16(float a, float b) {
    u32 r;
    asm("v_cvt_pk_bf16_f32 %0, %1, %2" : "=v"(r) : "v"(a), "v"(b));
    return r;
}

// ---------------- kernel 0: x2 init (0 for valid t, 1e30 for pad) ----------------
__global__ void init_x2(float* __restrict__ x2) {
    const int i = blockIdx.x * 256 + threadIdx.x;       // 128*832 = 106496
    if (i < B_DIM * T_PAD) x2[i] = ((i % T_PAD) < T_DIM) ? 0.f : 1e30f;
}

// ---------------- kernel 1: coalesced x -> fragment-major bf16 granules + exact x2 ----------
// block = (b, 32-c slice cq, t-half th). Reads 32 rows as LONG contiguous runs (no 64B scatter),
// LDS-transposes, stores granule runs of 1KB contiguous. Granule G = ((b*52+s)*4+k)*64+l holds
// x[b][c = k*32+(l>>4)*8 .. +8][t = s*16+(l&15)]  (r6-verified layout).
__global__ __launch_bounds__(256, 4) void prep_x(const float* __restrict__ x,
                                                 int4* __restrict__ xg,
                                                 float* __restrict__ x2) {
    const int o   = blockIdx.x;                // 1024; XCD-matched to gemm: XCD owns 16 b's
    const int xcd = o & 7, jj = o >> 3;        // jj: 0..127
    const int b   = xcd * 16 + (jj >> 3);
    const int r   = jj & 7;
    const int cq  = r >> 1, th = r & 1;
    const int c0  = cq * 32, t0 = th * 416;

    const int tid = threadIdx.x, w = tid >> 6, l = tid & 63;

    __shared__ __align__(16) u16   xt[32][420];   // [c-local][t-local], 840B rows
    __shared__ __align__(16) float x2l[4][416];   // per-wave x2 partials

    const float* xb = x + (size_t)b * C_DIM * T_DIM;

    float sq0[4] = {0.f, 0.f, 0.f, 0.f};
    float sq1[4] = {0.f, 0.f, 0.f, 0.f};

    // ---- phase 1: long-run coalesced reads; wave w owns c-rows 8w..8w+7 ----
#pragma unroll
    for (int rr = 0; rr < 8; ++rr) {
        const int cl = w * 8 + rr;
        const float* row = xb + (size_t)(c0 + cl) * T_DIM;
        // chunk A: t-local l*4 .. +3
        {
            const int tg = t0 + l * 4;
            float4u u;
            if (tg + 3 < T_DIM) u = *(const float4u*)(row + tg);
            else {
#pragma unroll
                for (int q = 0; q < 4; ++q) u[q] = (tg + q < T_DIM) ? row[tg + q] : 0.f;
            }
#pragma unroll
            for (int q = 0; q < 4; ++q) sq0[q] = fmaf(u[q], u[q], sq0[q]);
            *(uint2*)(&xt[cl][l * 4]) = make_uint2(cvt_pk_bf16(u[0], u[1]), cvt_pk_bf16(u[2], u[3]));
        }
        // chunk B: t-local 256 + l*4 (lanes 0..39)
        if (l < 40) {
            const int tg = t0 + 256 + l * 4;
            float4u u;
            if (tg + 3 < T_DIM) u = *(const float4u*)(row + tg);
            else {
#pragma unroll
                for (int q = 0; q < 4; ++q) u[q] = (tg + q < T_DIM) ? row[tg + q] : 0.f;
            }
#pragma unroll
            for (int q = 0; q < 4; ++q) sq1[q] = fmaf(u[q], u[q], sq1[q]);
            *(uint2*)(&xt[cl][256 + l * 4]) = make_uint2(cvt_pk_bf16(u[0], u[1]), cvt_pk_bf16(u[2], u[3]));
        }
    }
#pragma unroll
    for (int q = 0; q < 4; ++q) x2l[w][l * 4 + q] = sq0[q];
    if (l < 40) {
#pragma unroll
        for (int q = 0; q < 4; ++q) x2l[w][256 + l * 4 + q] = sq1[q];
    }
    __syncthreads();

    // ---- x2 flush: one coalesced atomic pass (4-way inter-block cq contention) ----
    for (int i = tid; i < 416; i += 256) {
        const float v = x2l[0][i] + x2l[1][i] + x2l[2][i] + x2l[3][i];
        atomicAdd(x2 + (size_t)b * T_PAD + t0 + i, v);
    }

    // ---- phase 2: granule emission, 1KB contiguous runs ----
    int4* dst = xg + ((size_t)(b * NS + th * SH) * 4 + cq) * 64;
    for (int j = tid; j < SH * 64; j += 256) {
        const int s  = j >> 6, ll = j & 63;
        const int tl = s * 16 + (ll & 15);
        const int cl = (ll >> 4) * 8;
        u32 d[4];
#pragma unroll
        for (int h = 0; h < 4; ++h)
            d[h] = (u32)xt[cl + 2 * h][tl] | ((u32)xt[cl + 2 * h + 1][tl] << 16);
        dst[(size_t)s * 256 + ll] = make_int4((int)d[0], (int)d[1], (int)d[2], (int)d[3]);
    }
}

// ---------------- kernel 2: barrier-free direct-fragment MFMA GEMM + min over t ----------------
// grid 1024 = b(128) x pt(4) x th(2); block 256 (4 waves); wave owns 32 protos in regs.
// 16 waves/CU, no LDS, no barriers; per step: 4 coalesced 1KB loads -> 8 MFMA -> pair-fold.
__global__ __launch_bounds__(256, 4) void gemm_min(
    const int4* __restrict__ xg,
    const float* __restrict__ x2,
    const float* __restrict__ proto,
    float* __restrict__ wsmin) {

    const int o   = blockIdx.x;               // XCD-bijective: 1024 = 8 XCD x 128
    const int xcd = o & 7, j = o >> 3;        // 0..127
    const int b   = xcd * 16 + (j >> 3);
    const int r   = j & 7;
    const int pt  = r >> 1, th = r & 1;

    const int tid = threadIdx.x;
    const int w = tid >> 6, l = tid & 63;
    const int row16 = l & 15, kq = l >> 4;
    const int wp = pt * 128 + w * 32;         // wave's proto base (32 rows)

    // ---- prototype A-frags (bf16) ----
    short8 afr[2][4];
#pragma unroll
    for (int ps = 0; ps < 2; ++ps) {
        const int rr = wp + ps * 16 + row16;
#pragma unroll
        for (int k = 0; k < 4; ++k) {
            const int k0 = k * 32 + kq * 8;
            union { short8 s; u32 d[4]; } t;
            if (rr < P_DIM) {
                float4 u0 = *(const float4*)(proto + rr * C_DIM + k0);
                float4 u1 = *(const float4*)(proto + rr * C_DIM + k0 + 4);
                t.d[0] = cvt_pk_bf16(u0.x, u0.y);
                t.d[1] = cvt_pk_bf16(u0.z, u0.w);
                t.d[2] = cvt_pk_bf16(u1.x, u1.y);
                t.d[3] = cvt_pk_bf16(u1.z, u1.w);
            } else {
                t.d[0] = t.d[1] = t.d[2] = t.d[3] = 0u;
            }
            afr[ps][k] = t.s;
        }
    }

    const int4*  gb = xg + (size_t)(b * NS + th * SH) * 256;
    const float* xw = x2 + (size_t)b * T_PAD + th * 416;

    f32x4 minv[2];
    minv[0] = (f32x4){1e30f, 1e30f, 1e30f, 1e30f};
    minv[1] = (f32x4){1e30f, 1e30f, 1e30f, 1e30f};

    short8 bA[4], bB[4];
    float  xa, xb_, xaN;

    auto LOAD = [&](short8 (&bf)[4], float& xv, int s) {
#pragma unroll
        for (int k = 0; k < 4; ++k)
            bf[k] = *(const short8*)(gb + (size_t)s * 256 + k * 64 + l);   // 1KB coalesced
        xv = xw[s * 16 + row16];
    };

    LOAD(bA, xa, 0);
    for (int it = 0; it < 13; ++it) {
        const int s = 2 * it;
        LOAD(bB, xb_, s + 1);

        f32x4 accA[2];
        accA[0] = (f32x4){0.f, 0.f, 0.f, 0.f};
        accA[1] = (f32x4){0.f, 0.f, 0.f, 0.f};
        __builtin_amdgcn_s_setprio(1);
#pragma unroll
        for (int k = 0; k < 4; ++k)
#pragma unroll
            for (int ps = 0; ps < 2; ++ps)
                accA[ps] = __builtin_amdgcn_mfma_f32_16x16x32_bf16(afr[ps][k], bA[k], accA[ps], 0, 0, 0);
        __builtin_amdgcn_s_setprio(0);

        if (s + 2 < SH) LOAD(bA, xaN, s + 2);

        f32x4 accB[2];
        accB[0] = (f32x4){0.f, 0.f, 0.f, 0.f};
        accB[1] = (f32x4){0.f, 0.f, 0.f, 0.f};
        __builtin_amdgcn_s_setprio(1);
#pragma unroll
        for (int k = 0; k < 4; ++k)
#pragma unroll
            for (int ps = 0; ps < 2; ++ps)
                accB[ps] = __builtin_amdgcn_mfma_f32_16x16x32_bf16(afr[ps][k], bB[k], accB[ps], 0, 0, 0);
        __builtin_amdgcn_s_setprio(0);

        // pair-fold: fminf(fminf(e0,e1), minv) -> v_min3_f32
#pragma unroll
        for (int ps = 0; ps < 2; ++ps)
#pragma unroll
            for (int q = 0; q < 4; ++q) {
                const float e0 = fmaf(-2.f, accA[ps][q], xa);
                const float e1 = fmaf(-2.f, accB[ps][q], xb_);
                minv[ps][q] = fminf(fminf(e0, e1), minv[ps][q]);
            }
        xa = xaN;
    }

    // min across the 16 t-columns (lane bits 0..3)
#pragma unroll
    for (int m = 1; m <= 8; m <<= 1)
#pragma unroll
        for (int ps = 0; ps < 2; ++ps)
#pragma unroll
            for (int q = 0; q < 4; ++q)
                minv[ps][q] = fminf(minv[ps][q], __shfl_xor(minv[ps][q], m));

    if (row16 == 0) {
#pragma unroll
        for (int ps = 0; ps < 2; ++ps) {
            const int p = wp + ps * 16 + kq * 4;   // C/D: row = kq*4+q
            *(float4*)(&wsmin[((size_t)th * B_DIM + b) * P_PAD + p]) =
                make_float4(minv[ps][0], minv[ps][1], minv[ps][2], minv[ps][3]);
        }
    }
}

// ---------------- kernel 3: p2 + 2-way min-merge + clamp + log-sim + @W ----------------
__global__ __launch_bounds__(256) void combine_logits(
    const float* __restrict__ proto, const float* __restrict__ lw,
    const float* __restrict__ wsmin, float* __restrict__ out) {
    const int b = blockIdx.x, tid = threadIdx.x;
    float a[NCLS] = {0.f, 0.f, 0.f, 0.f, 0.f};
    for (int p = tid; p < P_DIM; p += 256) {
        const float4* pr = (const float4*)(proto + p * C_DIM);
        float p2 = 0.f;
#pragma unroll
        for (int i = 0; i < 32; ++i) {
            float4 u = pr[i];
            p2 += u.x*u.x + u.y*u.y + u.z*u.z + u.w*u.w;
        }
        const float m0 = wsmin[((size_t)0 * B_DIM + b) * P_PAD + p];
        const float m1 = wsmin[((size_t)1 * B_DIM + b) * P_PAD + p];
        const float m  = fminf(m0, m1);
        const float md = fmaxf(m + p2, 0.f);
        const float sim = logf((md + 1.f) / (md + EPSV));
#pragma unroll
        for (int n = 0; n < NCLS; ++n) a[n] = fmaf(sim, lw[p * NCLS + n], a[n]);
    }
#pragma unroll
    for (int m = 1; m <= 32; m <<= 1)
#pragma unroll
        for (int n = 0; n < NCLS; ++n) a[n] += __shfl_xor(a[n], m);
    __shared__ float red[4][NCLS];
    const int w = tid >> 6, l = tid & 63;
    if (l == 0) {
#pragma unroll
        for (int n = 0; n < NCLS; ++n) red[w][n] = a[n];
    }
    __syncthreads();
    if (tid < NCLS)
        out[b * NCLS + tid] = red[0][tid] + red[1][tid] + red[2][tid] + red[3][tid];
}

// ---------------- fallback (no workspace): slow but correct ----------------
__global__ __launch_bounds__(256) void fallback_k(const float* __restrict__ x,
                                                  const float* __restrict__ proto,
                                                  const float* __restrict__ lw,
                                                  float* __restrict__ out) {
    __shared__ float x2s[T_DIM];
    __shared__ float sims[P_DIM];
    int b = blockIdx.x, tid = threadIdx.x;
    for (int t = tid; t < T_DIM; t += 256) {
        float a = 0.f;
        for (int c = 0; c < C_DIM; ++c) { float v = x[((size_t)b * C_DIM + c) * T_DIM + t]; a = fmaf(v, v, a); }
        x2s[t] = a;
    }
    __syncthreads();
    for (int p = tid; p < P_DIM; p += 256) {
        float p2 = 0.f;
        for (int c = 0; c < C_DIM; ++c) { float v = proto[p * C_DIM + c]; p2 = fmaf(v, v, p2); }
        float mind = 1e30f;
        for (int t = 0; t < T_DIM; ++t) {
            float xp = 0.f;
            for (int c = 0; c < C_DIM; ++c)
                xp = fmaf(x[((size_t)b * C_DIM + c) * T_DIM + t], proto[p * C_DIM + c], xp);
            float d = fmaxf(x2s[t] - 2.f * xp + p2, 0.f);
            mind = fminf(mind, d);
        }
        sims[p] = logf((mind + 1.f) / (mind + EPSV));
    }
    __syncthreads();
    if (tid < NCLS) {
        float a = 0.f;
        for (int p = 0; p < P_DIM; ++p) a = fmaf(sims[p], lw[p * NCLS + tid], a);
        out[b * NCLS + tid] = a;
    }
}

extern "C" void kernel_launch(void* const* d_in, const int* in_sizes, int n_in,
                              void* d_out, int out_size, void* d_ws, size_t ws_size,
                              hipStream_t stream) {
    const float* x     = (const float*)d_in[0];
    const float* proto = (const float*)d_in[1];
    const float* lw    = (const float*)d_in[2];
    float* out = (float*)d_out;

    const size_t xg_bytes = (size_t)B_DIM * NS * 4 * 64 * 16;        // 27,262,976
    const size_t x2_off   = xg_bytes;
    const size_t min_off  = x2_off + (size_t)B_DIM * T_PAD * 4;
    const size_t need     = min_off + (size_t)2 * B_DIM * P_PAD * 4; // ~28.2 MB

    if (ws_size >= need) {
        int4*  xg    = (int4*)d_ws;
        float* x2    = (float*)((char*)d_ws + x2_off);
        float* wsmin = (float*)((char*)d_ws + min_off);
        init_x2       <<<dim3(416),  256, 0, stream>>>(x2);
        prep_x        <<<dim3(1024), 256, 0, stream>>>(x, xg, x2);
        gemm_min      <<<dim3(1024), 256, 0, stream>>>(xg, x2, proto, wsmin);
        combine_logits<<<dim3(B_DIM), 256, 0, stream>>>(proto, lw, wsmin, out);
    } else {
        fallback_k<<<dim3(B_DIM), 256, 0, stream>>>(x, proto, lw, out);
    }
}

// Round 9
// 53.024 us; speedup vs baseline: 1.0405x; 1.0405x over previous
//
#include <hip/hip_runtime.h>
#include <hip/hip_bf16.h>

#define B_DIM 128
#define C_DIM 128
#define T_DIM 777
#define T_PAD 832   // 52 * 16
#define NS    52    // 16-t steps per b
#define SH    26    // steps per th half
#define P_DIM 500
#define P_PAD 512
#define NCLS  5
#define EPSV  1e-4f

typedef unsigned short u16;
typedef unsigned int   u32;
typedef __attribute__((ext_vector_type(8))) short short8;   // 8 bf16 = 4 VGPR
typedef __attribute__((ext_vector_type(4))) float f32x4;
typedef float float4u __attribute__((ext_vector_type(4), aligned(4)));  // stride 777 odd -> 4B align

__device__ __forceinline__ u32 cvt_pk_bf16(float a, float b) {
    u32 r;
    asm("v_cvt_pk_bf16_f32 %0, %1, %2" : "=v"(r) : "v"(a), "v"(b));
    return r;
}
__device__ __forceinline__ float bf2f(u16 h) { return __uint_as_float((u32)h << 16); }

// ---------------- kernel 1: coalesced x -> fragment-major bf16 granules + x2 partials ---------
// block = (b, 32-c slice cq, t-half th); grid 1024, XCD-matched to gemm (XCD owns 16 b's).
// Granule G = ((b*52+s)*4+k)*64+l holds x[b][c=k*32+(l>>4)*8 ..+8][t=s*16+(l&15)] (verified layout).
// x2part[cq][b][t] = partial sum of squares over this cq's 32 c's (from bf16 values; no atomics).
__global__ __launch_bounds__(256, 4) void prep_x(const float* __restrict__ x,
                                                 int4* __restrict__ xg,
                                                 float* __restrict__ x2part) {
    const int o   = blockIdx.x;                // 1024
    const int xcd = o & 7, jj = o >> 3;        // jj: 0..127
    const int b   = xcd * 16 + (jj >> 3);
    const int r   = jj & 7;
    const int cq  = r >> 1, th = r & 1;
    const int c0  = cq * 32, t0 = th * 416;

    const int tid = threadIdx.x;

    __shared__ __align__(16) u16 xt[32][420];  // [c-local][t-local], 840B rows

    const float* xb = x + (size_t)b * C_DIM * T_DIM;

    // ---- phase 1: flat divergence-free coalesced loads (32 rows x 104 float4) ----
#pragma unroll
    for (int k = 0; k < 13; ++k) {
        const int idx = k * 256 + tid;         // 0..3327
        const int row = idx / 104;
        const int col = idx - row * 104;       // float4 units
        const int tg  = t0 + col * 4;
        const float* rp = xb + (size_t)(c0 + row) * T_DIM;
        float4u u;
        if (tg + 3 < T_DIM) {
            u = *(const float4u*)(rp + tg);
        } else {
#pragma unroll
            for (int q = 0; q < 4; ++q) u[q] = (tg + q < T_DIM) ? rp[tg + q] : 0.f;
        }
        *(uint2*)(&xt[row][col * 4]) = make_uint2(cvt_pk_bf16(u[0], u[1]), cvt_pk_bf16(u[2], u[3]));
    }
    __syncthreads();

    // ---- phase 1.5: x2 partials from the bf16 tile (plain stores, per-cq slot) ----
    for (int i = tid; i < 416; i += 256) {
        float s = 0.f;
#pragma unroll
        for (int cl = 0; cl < 32; ++cl) {
            const float v = bf2f(xt[cl][i]);
            s = fmaf(v, v, s);
        }
        x2part[((size_t)cq * B_DIM + b) * T_PAD + t0 + i] = s;
    }

    // ---- phase 2: granule emission, contiguous coalesced 16B stores ----
    int4* dst = xg + ((size_t)(b * NS + th * SH) * 4 + cq) * 64;
    for (int j = tid; j < SH * 64; j += 256) {
        const int s  = j >> 6, ll = j & 63;
        const int tl = s * 16 + (ll & 15);
        const int cl = (ll >> 4) * 8;
        u32 d[4];
#pragma unroll
        for (int h = 0; h < 4; ++h)
            d[h] = (u32)xt[cl + 2 * h][tl] | ((u32)xt[cl + 2 * h + 1][tl] << 16);
        dst[(size_t)s * 256 + ll] = make_int4((int)d[0], (int)d[1], (int)d[2], (int)d[3]);
    }
}

// ---------------- kernel 2: barrier-free direct-fragment MFMA GEMM + min over t ----------------
// grid 1024 = b(128) x pt(4) x th(2); block 256 (4 waves); wave owns 32 protos in regs.
// 16 waves/CU, no LDS, no barriers; per step: 4 coalesced 1KB loads + 4 x2 loads -> 8 MFMA -> fold.
__global__ __launch_bounds__(256, 4) void gemm_min(
    const int4* __restrict__ xg,
    const float* __restrict__ x2part,
    const float* __restrict__ proto,
    float* __restrict__ wsmin) {

    const int o   = blockIdx.x;               // XCD-bijective: 1024 = 8 XCD x 128
    const int xcd = o & 7, j = o >> 3;        // 0..127
    const int b   = xcd * 16 + (j >> 3);
    const int r   = j & 7;
    const int pt  = r >> 1, th = r & 1;

    const int tid = threadIdx.x;
    const int w = tid >> 6, l = tid & 63;
    const int row16 = l & 15, kq = l >> 4;
    const int wp = pt * 128 + w * 32;         // wave's proto base (32 rows)

    // ---- prototype A-frags (bf16) ----
    short8 afr[2][4];
#pragma unroll
    for (int ps = 0; ps < 2; ++ps) {
        const int rr = wp + ps * 16 + row16;
#pragma unroll
        for (int k = 0; k < 4; ++k) {
            const int k0 = k * 32 + kq * 8;
            union { short8 s; u32 d[4]; } t;
            if (rr < P_DIM) {
                float4 u0 = *(const float4*)(proto + rr * C_DIM + k0);
                float4 u1 = *(const float4*)(proto + rr * C_DIM + k0 + 4);
                t.d[0] = cvt_pk_bf16(u0.x, u0.y);
                t.d[1] = cvt_pk_bf16(u0.z, u0.w);
                t.d[2] = cvt_pk_bf16(u1.x, u1.y);
                t.d[3] = cvt_pk_bf16(u1.z, u1.w);
            } else {
                t.d[0] = t.d[1] = t.d[2] = t.d[3] = 0u;
            }
            afr[ps][k] = t.s;
        }
    }

    const int4*  gb = xg + (size_t)(b * NS + th * SH) * 256;
    const float* xw = x2part + (size_t)b * T_PAD + th * 416;   // + cq*B_DIM*T_PAD per slice
    const size_t cqs = (size_t)B_DIM * T_PAD;

    f32x4 minv[2];
    minv[0] = (f32x4){1e30f, 1e30f, 1e30f, 1e30f};
    minv[1] = (f32x4){1e30f, 1e30f, 1e30f, 1e30f};

    short8 bA[4], bB[4];
    float  xa, xb_, xaN;

    auto LOAD = [&](short8 (&bf)[4], float& xv, int s) {
#pragma unroll
        for (int k = 0; k < 4; ++k)
            bf[k] = *(const short8*)(gb + (size_t)s * 256 + k * 64 + l);   // 1KB coalesced
        const int tl = s * 16 + row16;                                      // t-local in th half
        const float v = xw[tl] + xw[cqs + tl] + xw[2 * cqs + tl] + xw[3 * cqs + tl];
        xv = (th * 416 + tl < T_DIM) ? v : 1e30f;                           // pad never wins
    };

    LOAD(bA, xa, 0);
    for (int it = 0; it < 13; ++it) {
        const int s = 2 * it;
        LOAD(bB, xb_, s + 1);

        f32x4 accA[2];
        accA[0] = (f32x4){0.f, 0.f, 0.f, 0.f};
        accA[1] = (f32x4){0.f, 0.f, 0.f, 0.f};
        __builtin_amdgcn_s_setprio(1);
#pragma unroll
        for (int k = 0; k < 4; ++k)
#pragma unroll
            for (int ps = 0; ps < 2; ++ps)
                accA[ps] = __builtin_amdgcn_mfma_f32_16x16x32_bf16(afr[ps][k], bA[k], accA[ps], 0, 0, 0);
        __builtin_amdgcn_s_setprio(0);

        if (s + 2 < SH) LOAD(bA, xaN, s + 2);

        f32x4 accB[2];
        accB[0] = (f32x4){0.f, 0.f, 0.f, 0.f};
        accB[1] = (f32x4){0.f, 0.f, 0.f, 0.f};
        __builtin_amdgcn_s_setprio(1);
#pragma unroll
        for (int k = 0; k < 4; ++k)
#pragma unroll
            for (int ps = 0; ps < 2; ++ps)
                accB[ps] = __builtin_amdgcn_mfma_f32_16x16x32_bf16(afr[ps][k], bB[k], accB[ps], 0, 0, 0);
        __builtin_amdgcn_s_setprio(0);

        // pair-fold: fminf(fminf(e0,e1), minv) -> v_min3_f32
#pragma unroll
        for (int ps = 0; ps < 2; ++ps)
#pragma unroll
            for (int q = 0; q < 4; ++q) {
                const float e0 = fmaf(-2.f, accA[ps][q], xa);
                const float e1 = fmaf(-2.f, accB[ps][q], xb_);
                minv[ps][q] = fminf(fminf(e0, e1), minv[ps][q]);
            }
        xa = xaN;
    }

    // min across the 16 t-columns (lane bits 0..3)
#pragma unroll
    for (int m = 1; m <= 8; m <<= 1)
#pragma unroll
        for (int ps = 0; ps < 2; ++ps)
#pragma unroll
            for (int q = 0; q < 4; ++q)
                minv[ps][q] = fminf(minv[ps][q], __shfl_xor(minv[ps][q], m));

    if (row16 == 0) {
#pragma unroll
        for (int ps = 0; ps < 2; ++ps) {
            const int p = wp + ps * 16 + kq * 4;   // C/D: row = kq*4+q
            *(float4*)(&wsmin[((size_t)th * B_DIM + b) * P_PAD + p]) =
                make_float4(minv[ps][0], minv[ps][1], minv[ps][2], minv[ps][3]);
        }
    }
}

// ---------------- kernel 3: p2 + 2-way min-merge + clamp + log-sim + @W ----------------
__global__ __launch_bounds__(256) void combine_logits(
    const float* __restrict__ proto, const float* __restrict__ lw,
    const float* __restrict__ wsmin, float* __restrict__ out) {
    const int b = blockIdx.x, tid = threadIdx.x;
    float a[NCLS] = {0.f, 0.f, 0.f, 0.f, 0.f};
    for (int p = tid; p < P_DIM; p += 256) {
        const float4* pr = (const float4*)(proto + p * C_DIM);
        float p2 = 0.f;
#pragma unroll
        for (int i = 0; i < 32; ++i) {
            float4 u = pr[i];
            p2 += u.x*u.x + u.y*u.y + u.z*u.z + u.w*u.w;
        }
        const float m0 = wsmin[((size_t)0 * B_DIM + b) * P_PAD + p];
        const float m1 = wsmin[((size_t)1 * B_DIM + b) * P_PAD + p];
        const float m  = fminf(m0, m1);
        const float md = fmaxf(m + p2, 0.f);
        const float sim = logf((md + 1.f) / (md + EPSV));
#pragma unroll
        for (int n = 0; n < NCLS; ++n) a[n] = fmaf(sim, lw[p * NCLS + n], a[n]);
    }
#pragma unroll
    for (int m = 1; m <= 32; m <<= 1)
#pragma unroll
        for (int n = 0; n < NCLS; ++n) a[n] += __shfl_xor(a[n], m);
    __shared__ float red[4][NCLS];
    const int w = tid >> 6, l = tid & 63;
    if (l == 0) {
#pragma unroll
        for (int n = 0; n < NCLS; ++n) red[w][n] = a[n];
    }
    __syncthreads();
    if (tid < NCLS)
        out[b * NCLS + tid] = red[0][tid] + red[1][tid] + red[2][tid] + red[3][tid];
}

// ---------------- fallback (no workspace): slow but correct ----------------
__global__ __launch_bounds__(256) void fallback_k(const float* __restrict__ x,
                                                  const float* __restrict__ proto,
                                                  const float* __restrict__ lw,
                                                  float* __restrict__ out) {
    __shared__ float x2s[T_DIM];
    __shared__ float sims[P_DIM];
    int b = blockIdx.x, tid = threadIdx.x;
    for (int t = tid; t < T_DIM; t += 256) {
        float a = 0.f;
        for (int c = 0; c < C_DIM; ++c) { float v = x[((size_t)b * C_DIM + c) * T_DIM + t]; a = fmaf(v, v, a); }
        x2s[t] = a;
    }
    __syncthreads();
    for (int p = tid; p < P_DIM; p += 256) {
        float p2 = 0.f;
        for (int c = 0; c < C_DIM; ++c) { float v = proto[p * C_DIM + c]; p2 = fmaf(v, v, p2); }
        float mind = 1e30f;
        for (int t = 0; t < T_DIM; ++t) {
            float xp = 0.f;
            for (int c = 0; c < C_DIM; ++c)
                xp = fmaf(x[((size_t)b * C_DIM + c) * T_DIM + t], proto[p * C_DIM + c], xp);
            float d = fmaxf(x2s[t] - 2.f * xp + p2, 0.f);
            mind = fminf(mind, d);
        }
        sims[p] = logf((mind + 1.f) / (mind + EPSV));
    }
    __syncthreads();
    if (tid < NCLS) {
        float a = 0.f;
        for (int p = 0; p < P_DIM; ++p) a = fmaf(sims[p], lw[p * NCLS + tid], a);
        out[b * NCLS + tid] = a;
    }
}

extern "C" void kernel_launch(void* const* d_in, const int* in_sizes, int n_in,
                              void* d_out, int out_size, void* d_ws, size_t ws_size,
                              hipStream_t stream) {
    const float* x     = (const float*)d_in[0];
    const float* proto = (const float*)d_in[1];
    const float* lw    = (const float*)d_in[2];
    float* out = (float*)d_out;

    const size_t xg_bytes = (size_t)B_DIM * NS * 4 * 64 * 16;        // 27,262,976
    const size_t x2_off   = xg_bytes;
    const size_t min_off  = x2_off + (size_t)4 * B_DIM * T_PAD * 4;  // 4 cq partials
    const size_t need     = min_off + (size_t)2 * B_DIM * P_PAD * 4; // ~29.5 MB

    if (ws_size >= need) {
        int4*  xg     = (int4*)d_ws;
        float* x2part = (float*)((char*)d_ws + x2_off);
        float* wsmin  = (float*)((char*)d_ws + min_off);
        prep_x        <<<dim3(1024), 256, 0, stream>>>(x, xg, x2part);
        gemm_min      <<<dim3(1024), 256, 0, stream>>>(xg, x2part, proto, wsmin);
        combine_logits<<<dim3(B_DIM), 256, 0, stream>>>(proto, lw, wsmin, out);
    } else {
        fallback_k<<<dim3(B_DIM), 256, 0, stream>>>(x, proto, lw, out);
    }
}